// Round 2
// baseline (576.236 us; speedup 1.0000x reference)
//
#include <hip/hip_runtime.h>
#include <hip/hip_bf16.h>
#include <cstdint>

// MFMA fragment types (gfx950, 16x16x32 bf16): 8 bf16 in 4 VGPRs, 4 fp32 acc.
typedef __attribute__((ext_vector_type(8))) short bf16x8;
typedef __attribute__((ext_vector_type(4))) float f32x4;

#define NEGV -1e30f

__device__ __forceinline__ unsigned short f2bf(float f) {
    // round-to-nearest-even fp32 -> bf16 (inputs are finite randn; no NaN path needed)
    unsigned u = __builtin_bit_cast(unsigned, f);
    u += 0x7fffu + ((u >> 16) & 1u);
    return (unsigned short)(u >> 16);
}

// Pack all conv weights into B-operand fragment layout for mfma_f32_16x16x32_bf16.
// Column c = off_k + j*4 + f  (off: k2->0, k3->8, k4->20, k5->36), cols 56..63 zero.
// Element B[kglob][n] for lane L of (kstep, ntile): kglob = kstep*32 + (L>>4)*8 + j,
// n = ntile*16 + (L&15). Flat short index: ((kstep*4+nt)*64 + lane)*8 + j.
__global__ void prep_w_kernel(const float* __restrict__ w2, const float* __restrict__ w3,
                              const float* __restrict__ w4, const float* __restrict__ w5,
                              unsigned short* __restrict__ Wb) {
    int id = blockIdx.x * blockDim.x + threadIdx.x;
    if (id >= 24 * 4 * 64 * 8) return;
    int j     = id & 7;
    int lane  = (id >> 3) & 63;
    int nt    = (id >> 9) & 3;
    int kstep = id >> 11;
    int kglob = kstep * 32 + ((lane >> 4) & 3) * 8 + j;  // d in [0,768)
    int c     = nt * 16 + (lane & 15);                   // col in [0,64)
    float v = 0.f;
    if (c < 56) {
        int k, off; const float* w;
        if (c < 8)       { k = 2; off = 0;  w = w2; }
        else if (c < 20) { k = 3; off = 8;  w = w3; }
        else if (c < 36) { k = 4; off = 20; w = w4; }
        else             { k = 5; off = 36; w = w5; }
        int jj = (c - off) >> 2;
        int f  = (c - off) & 3;
        v = w[f * 768 * k + kglob * k + jj];             // w_k layout (F, D, k)
    }
    Wb[id] = f2bf(v);
}

// One block (1024 thr = 16 waves) per batch row b.
// Wave w: M-tile (w&7)*16..+16, N-half (w>>3): n-tiles 2*(w>>3), 2*(w>>3)+1.
// acc = 2 x f32x4 = 8 VGPRs/lane -> fits 64-VGPR cap -> 2 blocks/CU = 32 waves/CU.
// A rows read by 2 waves (both N-halves): second read is a same-block L2 hit.
__global__ void __launch_bounds__(1024, 8)
cnn_main_kernel(const int* __restrict__ x, const float* __restrict__ hidden,
                const unsigned short* __restrict__ Wb,
                const float* __restrict__ b2, const float* __restrict__ b3,
                const float* __restrict__ b4, const float* __restrict__ b5,
                const float* __restrict__ fc_w, const float* __restrict__ fc_b,
                float* __restrict__ out) {
    __shared__ int   order_s[128];
    __shared__ int   cnt_w[2];
    __shared__ int   len_s;
    __shared__ float P[128][65];      // +1 pad: conflict-free epilogue writes
    __shared__ float feats[16];

    const int b   = blockIdx.x;
    const int tid = threadIdx.x;

    // ---- Phase 1: compaction (threads 0..127, waves 0-1 fully active) ----
    int nonpad = 0, pre = 0;
    if (tid < 128) {
        order_s[tid] = 127;  // slots >= len: harmless (never read by valid conv windows)
        nonpad = (x[b * 128 + tid] != 0) ? 1 : 0;
        unsigned long long mask = __ballot(nonpad);
        int lane = tid & 63;
        pre = __popcll(mask & ((1ull << lane) - 1ull));
        if (lane == 0) cnt_w[tid >> 6] = (int)__popcll(mask);
    }
    __syncthreads();
    if (tid < 128) {
        if (nonpad) {
            int base = (tid >= 64) ? cnt_w[0] : 0;
            order_s[base + pre] = tid;
        }
        if (tid == 0) len_s = cnt_w[0] + cnt_w[1];
    }
    __syncthreads();

    // ---- Phase 2: GEMM, M=128 rows (this b), N=64, K=768 ----
    const int w    = tid >> 6;     // wave 0..15
    const int lane = tid & 63;
    const int lrow = lane & 15;
    const int quad = lane >> 4;
    const int mt   = w & 7;        // M-tile
    const int nh   = w >> 3;       // N-half (0 or 1)

    const int trow = mt * 16 + lrow;
    const int s    = order_s[trow];
    const float* pa = hidden + (size_t)(b * 128 + s) * 768 + quad * 8;
    const bf16x8* bp = (const bf16x8*)Wb + (nh * 2) * 64 + lane;  // frag(ks,nt) at (ks*4+nt)*64+lane

    f32x4 acc0 = (f32x4){0.f, 0.f, 0.f, 0.f};
    f32x4 acc1 = (f32x4){0.f, 0.f, 0.f, 0.f};

#pragma unroll 3
    for (int ks = 0; ks < 24; ++ks) {
        f32x4 alo = *(const f32x4*)(pa + ks * 32);
        f32x4 ahi = *(const f32x4*)(pa + ks * 32 + 4);
        bf16x8 bf0 = bp[ks * 256];
        bf16x8 bf1 = bp[ks * 256 + 64];
        bf16x8 af;
#pragma unroll
        for (int j = 0; j < 4; ++j) {
            af[j]     = (short)f2bf(alo[j]);
            af[j + 4] = (short)f2bf(ahi[j]);
        }
        acc0 = __builtin_amdgcn_mfma_f32_16x16x32_bf16(af, bf0, acc0, 0, 0, 0);
        acc1 = __builtin_amdgcn_mfma_f32_16x16x32_bf16(af, bf1, acc1, 0, 0, 0);
    }

    // Epilogue: C/D layout col = lane&15, row = (lane>>4)*4 + reg  [verified m89/m91]
#pragma unroll
    for (int r = 0; r < 4; ++r) {
        int t = mt * 16 + quad * 4 + r;
        P[t][(nh * 2) * 16 + lrow]     = acc0[r];
        P[t][(nh * 2 + 1) * 16 + lrow] = acc1[r];
    }
    __syncthreads();

    // ---- Phase 3: conv-sum + masked max-pool; 1 wave per (k,f) pair ----
    {
        const int kg  = w >> 2;              // 0..3 -> k = 2..5
        const int kk  = 2 + kg;
        const int off = (kg == 0) ? 0 : (kg == 1) ? 8 : (kg == 2) ? 20 : 36;
        const int f   = w & 3;
        const int len = len_s;
        float lm = NEGV;
        for (int t = lane; t <= len - kk; t += 64) {
            float v = 0.f;
#pragma unroll 5
            for (int j = 0; j < kk; ++j) v += P[t + j][off + j * 4 + f];
            lm = fmaxf(lm, v);
        }
#pragma unroll
        for (int o = 32; o > 0; o >>= 1) lm = fmaxf(lm, __shfl_down(lm, o));
        if (lane == 0) {
            const float* bk = (kg == 0) ? b2 : (kg == 1) ? b3 : (kg == 2) ? b4 : b5;
            feats[w] = lm + bk[f];   // max(conv)+b == max(conv+b); NEG+b == NEG in fp32
        }
    }
    __syncthreads();
    if (tid == 0) {
        float logit = fc_b[0];
#pragma unroll
        for (int i = 0; i < 16; ++i) logit += feats[i] * fc_w[i];
        out[b] = 1.f / (1.f + expf(-logit));
    }
}

extern "C" void kernel_launch(void* const* d_in, const int* in_sizes, int n_in,
                              void* d_out, int out_size, void* d_ws, size_t ws_size,
                              hipStream_t stream) {
    const int*   x      = (const int*)d_in[0];
    const float* hidden = (const float*)d_in[1];
    const float* w2     = (const float*)d_in[2];
    const float* b2     = (const float*)d_in[3];
    const float* w3     = (const float*)d_in[4];
    const float* b3     = (const float*)d_in[5];
    const float* w4     = (const float*)d_in[6];
    const float* b4     = (const float*)d_in[7];
    const float* w5     = (const float*)d_in[8];
    const float* b5     = (const float*)d_in[9];
    const float* fc_w   = (const float*)d_in[10];
    const float* fc_b   = (const float*)d_in[11];
    float* out = (float*)d_out;

    unsigned short* Wb = (unsigned short*)d_ws;  // 24*4*64*8 bf16 = 96 KB

    prep_w_kernel<<<(24 * 4 * 64 * 8 + 255) / 256, 256, 0, stream>>>(w2, w3, w4, w5, Wb);
    cnn_main_kernel<<<1024, 1024, 0, stream>>>(x, hidden, Wb, b2, b3, b4, b5, fc_w, fc_b, out);
}